// Round 13
// baseline (1147.697 us; speedup 1.0000x reference)
//
#include <hip/hip_runtime.h>

#define NB 64
#define NS 256
#define ND 2048
#define NH 16
#define NHD 128

typedef unsigned short ushort_t;
typedef __attribute__((ext_vector_type(8))) __bf16 bf16x8;
typedef __attribute__((ext_vector_type(4))) short shortx4;
typedef __attribute__((ext_vector_type(4))) float f32x4;
typedef __attribute__((ext_vector_type(4))) unsigned short ushortx4;

__device__ __forceinline__ unsigned short f2bf(float f) {
  union { float f; unsigned int u; } v; v.f = f;
  unsigned int r = v.u + 0x7FFFu + ((v.u >> 16) & 1u);
  return (unsigned short)(r >> 16);
}

__device__ __forceinline__ void gload16(const void* g, void* l) {
  __builtin_amdgcn_global_load_lds(
      (__attribute__((address_space(1))) void*)(void*)(g),
      (__attribute__((address_space(3))) void*)(l), 16, 0, 0);
}

__device__ __forceinline__ unsigned lds_off(const void* p) {
  return (unsigned)(size_t)(__attribute__((address_space(3))) const void*)p;
}

template<int OFF>
__device__ __forceinline__ shortx4 tr16(unsigned addr) {
  shortx4 d;
  asm volatile("ds_read_b64_tr_b16 %0, %1 offset:%2"
               : "=v"(d) : "v"(addr), "i"(OFF));
  return d;
}

// Fused cast: x (32768 blocks), w_qkv (12288), w_o (4096).
__global__ void cast3_f32_bf16(const float* __restrict__ x, const float* __restrict__ wq,
                               const float* __restrict__ wo, ushort_t* __restrict__ xb,
                               ushort_t* __restrict__ wqb, ushort_t* __restrict__ wob) {
  long bi = blockIdx.x;
  const float* src; ushort_t* dst;
  if (bi < 32768) { src = x; dst = xb; }
  else if (bi < 32768 + 12288) { bi -= 32768; src = wq; dst = wqb; }
  else { bi -= 32768 + 12288; src = wo; dst = wob; }
  const long i = (bi * 256 + threadIdx.x) * 4;
  float4 v = *reinterpret_cast<const float4*>(src + i);
  ushortx4 o;
  o.x = f2bf(v.x); o.y = f2bf(v.y); o.z = f2bf(v.z); o.w = f2bf(v.w);
  *reinterpret_cast<ushortx4*>(dst + i) = o;
}

// ---------------------------------------------------------------------------
// 256x256 tile GEMM, BK=64, 8 waves (2M x 4N), 2 K-tiles/iteration, 8-phase
// schedule with counted vmcnt (the untried fine-phase+counted cell; m201
// template). Tiles: even->buf0, odd->buf1 (64KB each: A 32KB + B 32KB,
// halves of 16KB; row r of a matrix at byte r*128 — same linear layout and
// R8-verified swizzle).
// Phase p = { ds_reads (<=12) ; stage 1 half-tile (2 gload16) ; barrier ;
//             lgkm(0) ; setprio(1) ; 16 MFMA quantum ; setprio(0) ;
//             [vmcnt(4) at ph3/ph7] ; barrier }
// Ledger (race-free by barriers, not timing):
//  ph0: read E:a[0-3],b[0-1]   ; stage O.B.h0 (it>0)   ; MFMA E-q0
//  ph1: read E:a2[0-3],b[2-3]  ; stage O.B.h1 (it>0)   ; MFMA E-q1
//  ph2:                          stage (E+2).A.h0       ; MFMA E-q2
//  ph3:                          stage (E+2).A.h1       ; MFMA E-q3 ; vmcnt(4)
//  ph4: read O:a[0-3],b[0-1]   ; stage (E+2).B.h0      ; MFMA O-q0
//  ph5: read O:a2[0-3],b[2-3]  ; stage (E+2).B.h1      ; MFMA O-q1
//  ph6:                          stage (O+2).A.h0       ; MFMA O-q2
//  ph7:                          stage (O+2).A.h1       ; MFMA O-q3 ; vmcnt(4)
// vmcnt(4)@ph3: outstanding = ph2+ph3 stages -> O's B (ph0/1) landed before
//   ph4 reads; also (prev ph6/7) O.A landed.  vmcnt(4)@ph7: outstanding =
//   ph6+ph7 -> (E+2) fully landed before next ph0.  Every stage targets a
//   slot whose readers drained >=1 barrier earlier.  Never vmcnt(0) in loop.
// MODE 0: fp32 C.  MODE 1: bf16 permuted qkv [3][B][H][S][HD].
// ---------------------------------------------------------------------------
template<int MODE>
__global__ __launch_bounds__(512, 2) void gemm256(const ushort_t* __restrict__ A,
                                                  const ushort_t* __restrict__ Bt,
                                                  float* __restrict__ Cf,
                                                  ushort_t* __restrict__ Cq,
                                                  int M, int N, int K) {
  extern __shared__ char smem[];   // 2 bufs * 65536B
  const int tid = threadIdx.x;
  const int wv = tid >> 6, lane = tid & 63;
  const int l15 = lane & 15, lg = lane >> 4;
  const int wm = wv >> 2, wn = wv & 3;     // 2 x 4 wave grid; wave tile 128x64

  // T1: bijective XCD-aware block swizzle
  const int nbn = N >> 8;
  const int nwg = (M >> 8) * nbn;
  const int bid = blockIdx.x;
  const int q8 = nwg >> 3, r8 = nwg & 7;
  const int xcd = bid & 7, lin = bid >> 3;
  const int wg = (xcd < r8 ? xcd * (q8 + 1) : r8 * (q8 + 1) + (xcd - r8) * q8) + lin;
  const int m0 = (wg / nbn) << 8;
  const int n0 = (wg % nbn) << 8;

  // staging source (per-lane pre-swizzled; LDS dest linear) — R8-verified
  const int srow = tid >> 3;                                  // 0..63
  const int sce = ((tid & 7) * 8) ^ ((srow & 7) << 3);        // elems
  const ushort_t* pa = A  + (long)(m0 + srow) * K + sce;
  const ushort_t* pb = Bt + (long)(n0 + srow) * K + sce;

  // ds_read byte-XOR — R8-verified
  const int cx = (l15 & 7) << 4;
  const int c0 = (lg * 16) ^ cx;
  const int c1 = (64 + lg * 16) ^ cx;

  f32x4 acc[8][4] = {};
  const int nkt = K >> 6;          // 32 (even)
  const int nit = nkt >> 1;

  // STAGE half H (0/1) of matrix (A/B) of tile T into buf (T&1)
#define STAGE_A(T_, H_)                                                        \
  { char* d_ = smem + ((T_) & 1) * 65536 + (H_) * 16384 + wv * 1024;           \
    gload16(pa + (long)((H_) * 128) * K + (long)(T_) * 64, d_);                \
    gload16(pa + (long)((H_) * 128 + 64) * K + (long)(T_) * 64, d_ + 8192); }
#define STAGE_B(T_, H_)                                                        \
  { char* d_ = smem + ((T_) & 1) * 65536 + 32768 + (H_) * 16384 + wv * 1024;   \
    gload16(pb + (long)((H_) * 128) * K + (long)(T_) * 64, d_);                \
    gload16(pb + (long)((H_) * 128 + 64) * K + (long)(T_) * 64, d_ + 8192); }

  // prologue: tiles 0 -> buf0, 1 -> buf1 (16 gloads), full drain once
  STAGE_A(0, 0) STAGE_A(0, 1) STAGE_B(0, 0) STAGE_B(0, 1)
  STAGE_A(1, 0) STAGE_A(1, 1) STAGE_B(1, 0) STAGE_B(1, 1)
  asm volatile("s_waitcnt vmcnt(0)" ::: "memory");
  __builtin_amdgcn_s_barrier();

  bf16x8 a[4][2], a2[4][2], b[4][2];
  const char* rbE = smem;
  const char* rbO = smem + 65536;

#define RD_A(DST_, RB_, ROFF_)                                                 \
  _Pragma("unroll")                                                            \
  for (int i_ = 0; i_ < 4; ++i_) {                                             \
    const char* base_ = (RB_) + (wm * 128 + (ROFF_) + i_ * 16 + l15) * 128;    \
    DST_[i_][0] = *reinterpret_cast<const bf16x8*>(base_ + c0);                \
    DST_[i_][1] = *reinterpret_cast<const bf16x8*>(base_ + c1);                \
  }
#define RD_B(RB_, J0_)                                                         \
  _Pragma("unroll")                                                            \
  for (int j_ = 0; j_ < 2; ++j_) {                                             \
    const char* base_ = (RB_) + 32768 + (wn * 64 + ((J0_) + j_) * 16 + l15) * 128; \
    b[(J0_) + j_][0] = *reinterpret_cast<const bf16x8*>(base_ + c0);           \
    b[(J0_) + j_][1] = *reinterpret_cast<const bf16x8*>(base_ + c1);           \
  }
#define QUANT(AI_, ARR_, J0_)                                                  \
  __builtin_amdgcn_s_setprio(1);                                               \
  _Pragma("unroll")                                                            \
  for (int kk_ = 0; kk_ < 2; ++kk_)                                            \
    _Pragma("unroll")                                                          \
    for (int i_ = 0; i_ < 4; ++i_)                                             \
      _Pragma("unroll")                                                        \
      for (int j_ = 0; j_ < 2; ++j_)                                           \
        acc[(AI_) + i_][(J0_) + j_] = __builtin_amdgcn_mfma_f32_16x16x32_bf16( \
            ARR_[i_][kk_], b[(J0_) + j_][kk_], acc[(AI_) + i_][(J0_) + j_], 0, 0, 0); \
  __builtin_amdgcn_s_setprio(0);
#define LGKM0 asm volatile("s_waitcnt lgkmcnt(0)" ::: "memory");               \
              __builtin_amdgcn_sched_barrier(0);
#define VM4   asm volatile("s_waitcnt vmcnt(4)" ::: "memory");                 \
              __builtin_amdgcn_sched_barrier(0);
#define BAR   __builtin_amdgcn_s_barrier();

  for (int it = 0; it < nit; ++it) {
    const int tE = 2 * it, tO = tE + 1;
    // ---- ph0 ----
    RD_A(a, rbE, 0) RD_B(rbE, 0)
    if (it > 0) STAGE_B(tO, 0)
    BAR LGKM0 QUANT(0, a, 0) BAR
    // ---- ph1 ----
    RD_A(a2, rbE, 64) RD_B(rbE, 2)
    if (it > 0) STAGE_B(tO, 1)
    BAR LGKM0 QUANT(0, a, 2) BAR
    // ---- ph2 ----
    if (tE + 2 < nkt) STAGE_A(tE + 2, 0)
    BAR QUANT(4, a2, 0) BAR
    // ---- ph3 ----
    if (tE + 2 < nkt) STAGE_A(tE + 2, 1)
    BAR QUANT(4, a2, 2) VM4 BAR
    // ---- ph4 ----
    RD_A(a, rbO, 0) RD_B(rbO, 0)
    if (tE + 2 < nkt) STAGE_B(tE + 2, 0)
    BAR LGKM0 QUANT(0, a, 0) BAR
    // ---- ph5 ----
    RD_A(a2, rbO, 64) RD_B(rbO, 2)
    if (tE + 2 < nkt) STAGE_B(tE + 2, 1)
    BAR LGKM0 QUANT(0, a, 2) BAR
    // ---- ph6 ----
    if (tO + 2 < nkt) STAGE_A(tO + 2, 0)
    BAR QUANT(4, a2, 0) BAR
    // ---- ph7 ----
    if (tO + 2 < nkt) STAGE_A(tO + 2, 1)
    BAR QUANT(4, a2, 2) VM4 BAR
  }
#undef STAGE_A
#undef STAGE_B
#undef RD_A
#undef RD_B
#undef QUANT
#undef LGKM0
#undef VM4
#undef BAR

  // epilogue: D frag col = l15 (n), rows = lg*4 + r
  #pragma unroll
  for (int k = 0; k < 8; ++k) {
    const int mrow = m0 + wm * 128 + k * 16 + lg * 4;
    #pragma unroll
    for (int j = 0; j < 4; ++j) {
      const int n = n0 + wn * 64 + j * 16 + l15;
      #pragma unroll
      for (int r = 0; r < 4; ++r) {
        const int m = mrow + r;
        const float v = acc[k][j][r];
        if (MODE == 0) {
          Cf[(long)m * N + n] = v;
        } else {
          const int tq = n >> 11, hh = (n >> 7) & 15, hd = n & 127;
          const int b_ = m >> 8, s = m & 255;
          Cq[((((long)tq * NB + b_) * NH + hh) * NS + s) * NHD + hd] = f2bf(v);
        }
      }
    }
  }
}

// ---------------------------------------------------------------------------
// Fused causal attention (R12 — passed; T10 tr-read V path, Model B addr).
// ---------------------------------------------------------------------------
__global__ __launch_bounds__(512, 2) void attn_fused(const ushort_t* __restrict__ qkv,
                                                     ushort_t* __restrict__ ctx) {
  __shared__ char vsm[32768];                 // 2 bufs x 16KB
  const int bh = blockIdx.x;
  const int b = bh >> 4, h = bh & 15;
  const int tid = threadIdx.x;
  const int wave = tid >> 6, lane = tid & 63;
  const int l15 = lane & 15, lg = lane >> 4;
  const long head_off = ((long)(b * NH + h)) * (NS * NHD);
  const ushort_t* Qp = qkv + head_off;
  const ushort_t* Kp = qkv + (long)NB * NH * NS * NHD + head_off;
  const ushort_t* Vp = qkv + 2L * NB * NH * NS * NHD + head_off;
  const int q0 = wave * 32;
  const int klast = (q0 + 31) >> 6;

  const int t7 = tid & 127;
  const int srowv = ((t7 >> 3) << 2) | ((t7 >> 1) & 3);
  const int vcol = (tid >> 7) * 16 + (t7 & 1) * 8;
  const ushort_t* vsrc = Vp + srowv * NHD + vcol;

  bf16x8 qf[2][4];
  #pragma unroll
  for (int ni = 0; ni < 2; ++ni)
    #pragma unroll
    for (int kk = 0; kk < 4; ++kk)
      qf[ni][kk] = *reinterpret_cast<const bf16x8*>(Qp + (q0 + ni * 16 + l15) * NHD + kk * 32 + lg * 8);

  f32x4 o[8][2] = {};
  float mstate[2] = {-1e30f, -1e30f};
  float lstate[2] = {0.f, 0.f};
  const float scale = 0.08838834764831845f;

  gload16(vsrc, vsm + wave * 1024);
  gload16(vsrc + 64, vsm + 8192 + wave * 1024);
  asm volatile("s_waitcnt vmcnt(0)" ::: "memory");
  __builtin_amdgcn_s_barrier();

  for (int kt = 0; kt < 4; ++kt) {
    if (kt + 1 < 4) {
      char* db = vsm + ((kt + 1) & 1) * 16384 + wave * 1024;
      const ushort_t* s = vsrc + (kt + 1) * 64 * NHD;
      gload16(s, db);
      gload16(s + 64, db + 8192);
    }
    shortx4 p[4][2];
    const bool act = (kt <= klast);
    if (act) {
      f32x4 st[4][2] = {};
      #pragma unroll
      for (int kk = 0; kk < 4; ++kk) {
        bf16x8 kf[4];
        #pragma unroll
        for (int mi = 0; mi < 4; ++mi)
          kf[mi] = *reinterpret_cast<const bf16x8*>(Kp + (kt * 64 + mi * 16 + l15) * NHD + kk * 32 + lg * 8);
        #pragma unroll
        for (int mi = 0; mi < 4; ++mi)
          #pragma unroll
          for (int ni = 0; ni < 2; ++ni)
            st[mi][ni] = __builtin_amdgcn_mfma_f32_16x16x32_bf16(kf[mi], qf[ni][kk], st[mi][ni], 0, 0, 0);
      }
      const bool dom = (kt == klast);
      #pragma unroll
      for (int mi = 0; mi < 4; ++mi)
        #pragma unroll
        for (int ni = 0; ni < 2; ++ni)
          #pragma unroll
          for (int r = 0; r < 4; ++r) {
            const int kc = kt * 64 + mi * 16 + lg * 4 + r;
            const int q = q0 + ni * 16 + l15;
            float v = st[mi][ni][r] * scale;
            if (dom && kc > q) v = -1e30f;
            st[mi][ni][r] = v;
          }
      #pragma unroll
      for (int ni = 0; ni < 2; ++ni) {
        float tmax = -1e30f;
        #pragma unroll
        for (int mi = 0; mi < 4; ++mi)
          #pragma unroll
          for (int r = 0; r < 4; ++r) tmax = fmaxf(tmax, st[mi][ni][r]);
        tmax = fmaxf(tmax, __shfl_xor(tmax, 16, 64));
        tmax = fmaxf(tmax, __shfl_xor(tmax, 32, 64));
        const float mnew = fmaxf(mstate[ni], tmax);
        const float alpha = __expf(mstate[ni] - mnew);
        float tsum = 0.f;
        #pragma unroll
        for (int mi = 0; mi < 4; ++mi)
          #pragma unroll
          for (int r = 0; r < 4; ++r) {
            const float pe = __expf(st[mi][ni][r] - mnew);
            st[mi][ni][r] = pe;
            tsum += pe;
          }
        tsum += __shfl_xor(tsum, 16, 64);
        tsum += __shfl_xor(tsum, 32, 64);
        lstate[ni] = lstate[ni] * alpha + tsum;
        mstate[ni] = mnew;
        #pragma unroll
        for (int f = 0; f < 8; ++f)
          #pragma unroll
          for (int r = 0; r < 4; ++r) o[f][ni][r] *= alpha;
        #pragma unroll
        for (int mi = 0; mi < 4; ++mi)
          #pragma unroll
          for (int r = 0; r < 4; ++r) p[mi][ni][r] = (short)f2bf(st[mi][ni][r]);
      }
      const unsigned va = lds_off(vsm) + (unsigned)((kt & 1) * 16384 + lane * 8);
#define PVF(F)                                                                  \
      {                                                                         \
        shortx4 v0 = tr16<(F)*2048 +    0>(va);                                 \
        shortx4 v1 = tr16<(F)*2048 +  512>(va);                                 \
        shortx4 v2 = tr16<(F)*2048 + 1024>(va);                                 \
        shortx4 v3 = tr16<(F)*2048 + 1536>(va);                                 \
        asm volatile("s_waitcnt lgkmcnt(0)" ::: "memory");                      \
        __builtin_amdgcn_sched_barrier(0);                                      \
        o[F][0] = __builtin_amdgcn_mfma_f32_16x16x16bf16_1k(v0, p[0][0], o[F][0], 0, 0, 0); \
        o[F][1] = __builtin_amdgcn_mfma_f32_16x16x16bf16_1k(v0, p[0][1], o[F][1], 0, 0, 0); \
        o[F][0] = __builtin_amdgcn_mfma_f32_16x16x16bf16_1k(v1, p[1][0], o[F][0], 0, 0, 0); \
        o[F][1] = __builtin_amdgcn_mfma_f32_16x16x16bf16_1k(v1, p[1][1], o[F][1], 0, 0, 0); \
        o[F][0] = __builtin_amdgcn_mfma_f32_16x16x16bf16_1k(v2, p[2][0], o[F][0], 0, 0, 0); \
        o[F][1] = __builtin_amdgcn_mfma_f32_16x16x16bf16_1k(v2, p[2][1], o[F][1], 0, 0, 0); \
        o[F][0] = __builtin_amdgcn_mfma_f32_16x16x16bf16_1k(v3, p[3][0], o[F][0], 0, 0, 0); \
        o[F][1] = __builtin_amdgcn_mfma_f32_16x16x16bf16_1k(v3, p[3][1], o[F][1], 0, 0, 0); \
      }
      PVF(0) PVF(1) PVF(2) PVF(3) PVF(4) PVF(5) PVF(6) PVF(7)
#undef PVF
    }
    asm volatile("s_waitcnt vmcnt(0)" ::: "memory");
    __builtin_amdgcn_s_barrier();
  }

  const float inv0 = 1.f / lstate[0], inv1 = 1.f / lstate[1];
  #pragma unroll
  for (int f = 0; f < 8; ++f)
    #pragma unroll
    for (int ni = 0; ni < 2; ++ni) {
      const float inv = ni ? inv1 : inv0;
      const int q = q0 + ni * 16 + l15;
      const int hd = f * 16 + lg * 4;
      ushortx4 ov;
      #pragma unroll
      for (int r = 0; r < 4; ++r) ov[r] = f2bf(o[f][ni][r] * inv);
      *reinterpret_cast<ushortx4*>(ctx + ((long)(b * NS + q)) * ND + h * NHD + hd) = ov;
    }
}

extern "C" void kernel_launch(void* const* d_in, const int* in_sizes, int n_in,
                              void* d_out, int out_size, void* d_ws, size_t ws_size,
                              hipStream_t stream) {
  const float* x     = (const float*)d_in[0];
  const float* w_qkv = (const float*)d_in[1];
  const float* w_o   = (const float*)d_in[2];
  char* ws = (char*)d_ws;
  if (ws_size < 369098752UL) return;
  ushort_t* xb    = (ushort_t*)(ws);
  ushort_t* wqkvb = (ushort_t*)(ws + 67108864L);
  ushort_t* wob   = (ushort_t*)(ws + 92274688L);
  ushort_t* qkvb  = (ushort_t*)(ws + 100663296L);
  ushort_t* ctxb  = (ushort_t*)(ws + 301989888L);

  cast3_f32_bf16<<<dim3(49152), 256, 0, stream>>>(x, w_qkv, w_o, xb, wqkvb, wob);

  const int lds_bytes = 2 * 65536;  // 128 KiB
  (void)hipFuncSetAttribute(reinterpret_cast<const void*>(&gemm256<1>),
                            hipFuncAttributeMaxDynamicSharedMemorySize, lds_bytes);
  (void)hipFuncSetAttribute(reinterpret_cast<const void*>(&gemm256<0>),
                            hipFuncAttributeMaxDynamicSharedMemorySize, lds_bytes);

  // qkv = x @ w_qkv^T  -> permuted bf16 [3][B][H][S][HD]
  gemm256<1><<<dim3(64 * 24), 512, lds_bytes, stream>>>(xb, wqkvb, nullptr, qkvb,
                                                        NB * NS, 3 * ND, ND);
  // fused causal attention -> ctx bf16 [B][S][D]
  attn_fused<<<dim3(NB * NH), 512, 0, stream>>>(qkvb, ctxb);
  // out = ctx @ w_o^T  (fp32)
  gemm256<0><<<dim3(64 * 8), 512, lds_bytes, stream>>>(ctxb, wob, (float*)d_out, nullptr,
                                                       NB * NS, ND, ND);
}

// Round 14
// 675.585 us; speedup vs baseline: 1.6988x; 1.6988x over previous
//
#include <hip/hip_runtime.h>

#define NB 64
#define NS 256
#define ND 2048
#define NH 16
#define NHD 128

typedef unsigned short ushort_t;
typedef __attribute__((ext_vector_type(8))) __bf16 bf16x8;
typedef __attribute__((ext_vector_type(4))) short shortx4;
typedef __attribute__((ext_vector_type(4))) float f32x4;
typedef __attribute__((ext_vector_type(4))) unsigned short ushortx4;

__device__ __forceinline__ unsigned short f2bf(float f) {
  union { float f; unsigned int u; } v; v.f = f;
  unsigned int r = v.u + 0x7FFFu + ((v.u >> 16) & 1u);
  return (unsigned short)(r >> 16);
}

__device__ __forceinline__ void gload16(const void* g, void* l) {
  __builtin_amdgcn_global_load_lds(
      (__attribute__((address_space(1))) void*)(void*)(g),
      (__attribute__((address_space(3))) void*)(l), 16, 0, 0);
}

__device__ __forceinline__ unsigned lds_off(const void* p) {
  return (unsigned)(size_t)(__attribute__((address_space(3))) const void*)p;
}

template<int OFF>
__device__ __forceinline__ shortx4 tr16(unsigned addr) {
  shortx4 d;
  asm volatile("ds_read_b64_tr_b16 %0, %1 offset:%2"
               : "=v"(d) : "v"(addr), "i"(OFF));
  return d;
}

// Fused cast: x (32768 blocks), w_qkv (12288), w_o (4096).
__global__ void cast3_f32_bf16(const float* __restrict__ x, const float* __restrict__ wq,
                               const float* __restrict__ wo, ushort_t* __restrict__ xb,
                               ushort_t* __restrict__ wqb, ushort_t* __restrict__ wob) {
  long bi = blockIdx.x;
  const float* src; ushort_t* dst;
  if (bi < 32768) { src = x; dst = xb; }
  else if (bi < 32768 + 12288) { bi -= 32768; src = wq; dst = wqb; }
  else { bi -= 32768 + 12288; src = wo; dst = wob; }
  const long i = (bi * 256 + threadIdx.x) * 4;
  float4 v = *reinterpret_cast<const float4*>(src + i);
  ushortx4 o;
  o.x = f2bf(v.x); o.y = f2bf(v.y); o.z = f2bf(v.z); o.w = f2bf(v.w);
  *reinterpret_cast<ushortx4*>(dst + i) = o;
}

// ---------------------------------------------------------------------------
// 256x256 tile GEMM, BK=64, 8 waves (2M x 4N), 2-buffer ring.
// Round-14 change (vs R8/R12): REMOVE the forced lgkmcnt(0)+sched_barrier
// drain before the MFMA cluster. Those fences are only required for
// inline-asm ds_reads (rule #18); ours are plain loads — the compiler emits
// fine-grained counted lgkmcnt (m97 finding), letting early MFMAs overlap
// the tail of the 24-read drain. Reads ordered af[0], bf[0..3], af[1..7] so
// the first MFMA's operands complete earliest (~14 reads outstanding at
// first MFMA). DMA->ds_read dependency protected by __syncthreads() at tile
// end (drains vmcnt(0) + barrier). R13's 8-phase port spilled acc (657MB
// scratch writes) — schedule family closed at this structure.
// T2 swizzle + T1 XCD swizzle unchanged (R8-verified).
// MODE 0: fp32 C.  MODE 1: bf16 permuted qkv [3][B][H][S][HD].
// ---------------------------------------------------------------------------
template<int MODE>
__global__ __launch_bounds__(512, 2) void gemm256(const ushort_t* __restrict__ A,
                                                  const ushort_t* __restrict__ Bt,
                                                  float* __restrict__ Cf,
                                                  ushort_t* __restrict__ Cq,
                                                  int M, int N, int K) {
  extern __shared__ char smem[];   // 2 bufs * 65536B; A at +0 (32KB), B at +32768
  const int tid = threadIdx.x;
  const int wv = tid >> 6, lane = tid & 63;
  const int l15 = lane & 15, lg = lane >> 4;
  const int wm = wv >> 2, wn = wv & 3;

  const int nbn = N >> 8;
  const int nwg = (M >> 8) * nbn;
  const int bid = blockIdx.x;
  const int q8 = nwg >> 3, r8 = nwg & 7;
  const int xcd = bid & 7, lin = bid >> 3;
  const int wg = (xcd < r8 ? xcd * (q8 + 1) : r8 * (q8 + 1) + (xcd - r8) * q8) + lin;
  const int m0 = (wg / nbn) << 8;
  const int n0 = (wg % nbn) << 8;

  const int srow = tid >> 3;
  const int sce = ((tid & 7) * 8) ^ ((srow & 7) << 3);
  const ushort_t* pa = A  + (long)(m0 + srow) * K + sce;
  const ushort_t* pb = Bt + (long)(n0 + srow) * K + sce;

  const int cx = (l15 & 7) << 4;
  const int c0 = (lg * 16) ^ cx;
  const int c1 = (64 + lg * 16) ^ cx;

  f32x4 acc[8][4] = {};
  const int nkt = K >> 6;

  #pragma unroll
  for (int ch = 0; ch < 4; ++ch) {
    gload16(pa + (long)(ch * 64) * K, smem + ch * 8192 + wv * 1024);
    gload16(pb + (long)(ch * 64) * K, smem + 32768 + ch * 8192 + wv * 1024);
  }
  __syncthreads();   // drains the staging DMA (vmcnt) + barrier

  for (int t = 0; t < nkt; ++t) {
    const char* rb = smem + (t & 1) * 65536;
    const long kof = (long)t * 64;
    if (t + 1 < nkt) {
      char* db = smem + ((t + 1) & 1) * 65536 + wv * 1024;
      #pragma unroll
      for (int ch = 0; ch < 4; ++ch) {
        gload16(pa + (long)(ch * 64) * K + kof + 64, db + ch * 8192);
        gload16(pb + (long)(ch * 64) * K + kof + 64, db + 32768 + ch * 8192);
      }
    }
    bf16x8 af[8][2], bf[4][2];
    // read order: first-MFMA operands first -> compiler's counted lgkmcnt
    // lets MFMAs start with the rest of the reads still in flight
    {
      const char* base = rb + (wm * 128 + l15) * 128;
      af[0][0] = *reinterpret_cast<const bf16x8*>(base + c0);
      af[0][1] = *reinterpret_cast<const bf16x8*>(base + c1);
    }
    #pragma unroll
    for (int j = 0; j < 4; ++j) {
      const char* base = rb + 32768 + (wn * 64 + j * 16 + l15) * 128;
      bf[j][0] = *reinterpret_cast<const bf16x8*>(base + c0);
      bf[j][1] = *reinterpret_cast<const bf16x8*>(base + c1);
    }
    #pragma unroll
    for (int i = 1; i < 8; ++i) {
      const char* base = rb + (wm * 128 + i * 16 + l15) * 128;
      af[i][0] = *reinterpret_cast<const bf16x8*>(base + c0);
      af[i][1] = *reinterpret_cast<const bf16x8*>(base + c1);
    }
    __builtin_amdgcn_s_setprio(1);
    #pragma unroll
    for (int kk = 0; kk < 2; ++kk)
      #pragma unroll
      for (int i = 0; i < 8; ++i)
        #pragma unroll
        for (int j = 0; j < 4; ++j)
          acc[i][j] = __builtin_amdgcn_mfma_f32_16x16x32_bf16(af[i][kk], bf[j][kk], acc[i][j], 0, 0, 0);
    __builtin_amdgcn_s_setprio(0);
    __syncthreads();   // vmcnt(0) drain (stage landed long ago) + barrier
  }

  #pragma unroll
  for (int k = 0; k < 8; ++k) {
    const int mrow = m0 + wm * 128 + k * 16 + lg * 4;
    #pragma unroll
    for (int j = 0; j < 4; ++j) {
      const int n = n0 + wn * 64 + j * 16 + l15;
      #pragma unroll
      for (int r = 0; r < 4; ++r) {
        const int m = mrow + r;
        const float v = acc[k][j][r];
        if (MODE == 0) {
          Cf[(long)m * N + n] = v;
        } else {
          const int tq = n >> 11, hh = (n >> 7) & 15, hd = n & 127;
          const int b = m >> 8, s = m & 255;
          Cq[((((long)tq * NB + b) * NH + hh) * NS + s) * NHD + hd] = f2bf(v);
        }
      }
    }
  }
}

// ---------------------------------------------------------------------------
// Fused causal attention (R12 — verified; T10 tr-read V path, Model B addr).
// ---------------------------------------------------------------------------
__global__ __launch_bounds__(512, 2) void attn_fused(const ushort_t* __restrict__ qkv,
                                                     ushort_t* __restrict__ ctx) {
  __shared__ char vsm[32768];                 // 2 bufs x 16KB
  const int bh = blockIdx.x;
  const int b = bh >> 4, h = bh & 15;
  const int tid = threadIdx.x;
  const int wave = tid >> 6, lane = tid & 63;
  const int l15 = lane & 15, lg = lane >> 4;
  const long head_off = ((long)(b * NH + h)) * (NS * NHD);
  const ushort_t* Qp = qkv + head_off;
  const ushort_t* Kp = qkv + (long)NB * NH * NS * NHD + head_off;
  const ushort_t* Vp = qkv + 2L * NB * NH * NS * NHD + head_off;
  const int q0 = wave * 32;
  const int klast = (q0 + 31) >> 6;

  const int t7 = tid & 127;
  const int srowv = ((t7 >> 3) << 2) | ((t7 >> 1) & 3);
  const int vcol = (tid >> 7) * 16 + (t7 & 1) * 8;
  const ushort_t* vsrc = Vp + srowv * NHD + vcol;

  bf16x8 qf[2][4];
  #pragma unroll
  for (int ni = 0; ni < 2; ++ni)
    #pragma unroll
    for (int kk = 0; kk < 4; ++kk)
      qf[ni][kk] = *reinterpret_cast<const bf16x8*>(Qp + (q0 + ni * 16 + l15) * NHD + kk * 32 + lg * 8);

  f32x4 o[8][2] = {};
  float mstate[2] = {-1e30f, -1e30f};
  float lstate[2] = {0.f, 0.f};
  const float scale = 0.08838834764831845f;

  gload16(vsrc, vsm + wave * 1024);
  gload16(vsrc + 64, vsm + 8192 + wave * 1024);
  asm volatile("s_waitcnt vmcnt(0)" ::: "memory");
  __builtin_amdgcn_s_barrier();

  for (int kt = 0; kt < 4; ++kt) {
    if (kt + 1 < 4) {
      char* db = vsm + ((kt + 1) & 1) * 16384 + wave * 1024;
      const ushort_t* s = vsrc + (kt + 1) * 64 * NHD;
      gload16(s, db);
      gload16(s + 64, db + 8192);
    }
    shortx4 p[4][2];
    const bool act = (kt <= klast);
    if (act) {
      f32x4 st[4][2] = {};
      #pragma unroll
      for (int kk = 0; kk < 4; ++kk) {
        bf16x8 kf[4];
        #pragma unroll
        for (int mi = 0; mi < 4; ++mi)
          kf[mi] = *reinterpret_cast<const bf16x8*>(Kp + (kt * 64 + mi * 16 + l15) * NHD + kk * 32 + lg * 8);
        #pragma unroll
        for (int mi = 0; mi < 4; ++mi)
          #pragma unroll
          for (int ni = 0; ni < 2; ++ni)
            st[mi][ni] = __builtin_amdgcn_mfma_f32_16x16x32_bf16(kf[mi], qf[ni][kk], st[mi][ni], 0, 0, 0);
      }
      const bool dom = (kt == klast);
      #pragma unroll
      for (int mi = 0; mi < 4; ++mi)
        #pragma unroll
        for (int ni = 0; ni < 2; ++ni)
          #pragma unroll
          for (int r = 0; r < 4; ++r) {
            const int kc = kt * 64 + mi * 16 + lg * 4 + r;
            const int q = q0 + ni * 16 + l15;
            float v = st[mi][ni][r] * scale;
            if (dom && kc > q) v = -1e30f;
            st[mi][ni][r] = v;
          }
      #pragma unroll
      for (int ni = 0; ni < 2; ++ni) {
        float tmax = -1e30f;
        #pragma unroll
        for (int mi = 0; mi < 4; ++mi)
          #pragma unroll
          for (int r = 0; r < 4; ++r) tmax = fmaxf(tmax, st[mi][ni][r]);
        tmax = fmaxf(tmax, __shfl_xor(tmax, 16, 64));
        tmax = fmaxf(tmax, __shfl_xor(tmax, 32, 64));
        const float mnew = fmaxf(mstate[ni], tmax);
        const float alpha = __expf(mstate[ni] - mnew);
        float tsum = 0.f;
        #pragma unroll
        for (int mi = 0; mi < 4; ++mi)
          #pragma unroll
          for (int r = 0; r < 4; ++r) {
            const float pe = __expf(st[mi][ni][r] - mnew);
            st[mi][ni][r] = pe;
            tsum += pe;
          }
        tsum += __shfl_xor(tsum, 16, 64);
        tsum += __shfl_xor(tsum, 32, 64);
        lstate[ni] = lstate[ni] * alpha + tsum;
        mstate[ni] = mnew;
        #pragma unroll
        for (int f = 0; f < 8; ++f)
          #pragma unroll
          for (int r = 0; r < 4; ++r) o[f][ni][r] *= alpha;
        #pragma unroll
        for (int mi = 0; mi < 4; ++mi)
          #pragma unroll
          for (int r = 0; r < 4; ++r) p[mi][ni][r] = (short)f2bf(st[mi][ni][r]);
      }
      const unsigned va = lds_off(vsm) + (unsigned)((kt & 1) * 16384 + lane * 8);
#define PVF(F)                                                                  \
      {                                                                         \
        shortx4 v0 = tr16<(F)*2048 +    0>(va);                                 \
        shortx4 v1 = tr16<(F)*2048 +  512>(va);                                 \
        shortx4 v2 = tr16<(F)*2048 + 1024>(va);                                 \
        shortx4 v3 = tr16<(F)*2048 + 1536>(va);                                 \
        asm volatile("s_waitcnt lgkmcnt(0)" ::: "memory");                      \
        __builtin_amdgcn_sched_barrier(0);                                      \
        o[F][0] = __builtin_amdgcn_mfma_f32_16x16x16bf16_1k(v0, p[0][0], o[F][0], 0, 0, 0); \
        o[F][1] = __builtin_amdgcn_mfma_f32_16x16x16bf16_1k(v0, p[0][1], o[F][1], 0, 0, 0); \
        o[F][0] = __builtin_amdgcn_mfma_f32_16x16x16bf16_1k(v1, p[1][0], o[F][0], 0, 0, 0); \
        o[F][1] = __builtin_amdgcn_mfma_f32_16x16x16bf16_1k(v1, p[1][1], o[F][1], 0, 0, 0); \
        o[F][0] = __builtin_amdgcn_mfma_f32_16x16x16bf16_1k(v2, p[2][0], o[F][0], 0, 0, 0); \
        o[F][1] = __builtin_amdgcn_mfma_f32_16x16x16bf16_1k(v2, p[2][1], o[F][1], 0, 0, 0); \
        o[F][0] = __builtin_amdgcn_mfma_f32_16x16x16bf16_1k(v3, p[3][0], o[F][0], 0, 0, 0); \
        o[F][1] = __builtin_amdgcn_mfma_f32_16x16x16bf16_1k(v3, p[3][1], o[F][1], 0, 0, 0); \
      }
      PVF(0) PVF(1) PVF(2) PVF(3) PVF(4) PVF(5) PVF(6) PVF(7)
#undef PVF
    }
    asm volatile("s_waitcnt vmcnt(0)" ::: "memory");
    __builtin_amdgcn_s_barrier();
  }

  const float inv0 = 1.f / lstate[0], inv1 = 1.f / lstate[1];
  #pragma unroll
  for (int f = 0; f < 8; ++f)
    #pragma unroll
    for (int ni = 0; ni < 2; ++ni) {
      const float inv = ni ? inv1 : inv0;
      const int q = q0 + ni * 16 + l15;
      const int hd = f * 16 + lg * 4;
      ushortx4 ov;
      #pragma unroll
      for (int r = 0; r < 4; ++r) ov[r] = f2bf(o[f][ni][r] * inv);
      *reinterpret_cast<ushortx4*>(ctx + ((long)(b * NS + q)) * ND + h * NHD + hd) = ov;
    }
}

extern "C" void kernel_launch(void* const* d_in, const int* in_sizes, int n_in,
                              void* d_out, int out_size, void* d_ws, size_t ws_size,
                              hipStream_t stream) {
  const float* x     = (const float*)d_in[0];
  const float* w_qkv = (const float*)d_in[1];
  const float* w_o   = (const float*)d_in[2];
  char* ws = (char*)d_ws;
  if (ws_size < 369098752UL) return;
  ushort_t* xb    = (ushort_t*)(ws);
  ushort_t* wqkvb = (ushort_t*)(ws + 67108864L);
  ushort_t* wob   = (ushort_t*)(ws + 92274688L);
  ushort_t* qkvb  = (ushort_t*)(ws + 100663296L);
  ushort_t* ctxb  = (ushort_t*)(ws + 301989888L);

  cast3_f32_bf16<<<dim3(49152), 256, 0, stream>>>(x, w_qkv, w_o, xb, wqkvb, wob);

  const int lds_bytes = 2 * 65536;  // 128 KiB
  (void)hipFuncSetAttribute(reinterpret_cast<const void*>(&gemm256<1>),
                            hipFuncAttributeMaxDynamicSharedMemorySize, lds_bytes);
  (void)hipFuncSetAttribute(reinterpret_cast<const void*>(&gemm256<0>),
                            hipFuncAttributeMaxDynamicSharedMemorySize, lds_bytes);

  // qkv = x @ w_qkv^T  -> permuted bf16 [3][B][H][S][HD]
  gemm256<1><<<dim3(64 * 24), 512, lds_bytes, stream>>>(xb, wqkvb, nullptr, qkvb,
                                                        NB * NS, 3 * ND, ND);
  // fused causal attention -> ctx bf16 [B][S][D]
  attn_fused<<<dim3(NB * NH), 512, 0, stream>>>(qkvb, ctxb);
  // out = ctx @ w_o^T  (fp32)
  gemm256<0><<<dim3(64 * 8), 512, lds_bytes, stream>>>(ctxb, wob, (float*)d_out, nullptr,
                                                       NB * NS, ND, ND);
}